// Round 3
// baseline (1081.338 us; speedup 1.0000x reference)
//
#include <hip/hip_runtime.h>
#include <stdint.h>

#define DIM   512
#define CBSZ  8192
#define BN    8192      // B*N = 4*2048
#define LDSS  132       // padded LDS row stride (132*4 B = 33*16 -> float4 aligned)

// Monotone float->uint mapping: order of floats (incl. negatives) == unsigned order.
__device__ __forceinline__ unsigned int fkey(float v) {
  unsigned int u = __float_as_uint(v);
  return (u & 0x80000000u) ? ~u : (u | 0x80000000u);
}

// ---------------------------------------------------------------------------
// Kernel A: implicit = codebook @ W^T  (both row-major along K=d), plus
// c2[c] = sum_e implicit[c][e]^2 accumulated via atomics.
// 128x128 tile, K-tile 32, 256 threads, 8x8 micro-tile, f32 vector FMA.
// ---------------------------------------------------------------------------
__global__ __launch_bounds__(256) void k_implicit(
    const float* __restrict__ cb, const float* __restrict__ Wm,
    float* __restrict__ imp, float* __restrict__ c2) {
  __shared__ float As[32][LDSS];
  __shared__ float Bs[32][LDSS];
  const int t  = threadIdx.x;
  const int tx = t & 15, ty = t >> 4;
  const int tm0 = blockIdx.x * 128;   // codebook rows
  const int tn0 = blockIdx.y * 128;   // output cols (= W rows)
  float acc[8][8];
#pragma unroll
  for (int i = 0; i < 8; ++i)
#pragma unroll
    for (int j = 0; j < 8; ++j) acc[i][j] = 0.f;

  const int chunk = t & 7, row0 = t >> 3;   // 8 k-chunks x 32 rows per round
  for (int kt = 0; kt < DIM; kt += 32) {
#pragma unroll
    for (int rr = 0; rr < 4; ++rr) {
      int row = row0 + rr * 32;
      float4 av = *(const float4*)(cb + (size_t)(tm0 + row) * DIM + kt + chunk * 4);
      float4 bv = *(const float4*)(Wm + (size_t)(tn0 + row) * DIM + kt + chunk * 4);
      As[chunk*4+0][row] = av.x; As[chunk*4+1][row] = av.y;
      As[chunk*4+2][row] = av.z; As[chunk*4+3][row] = av.w;
      Bs[chunk*4+0][row] = bv.x; Bs[chunk*4+1][row] = bv.y;
      Bs[chunk*4+2][row] = bv.z; Bs[chunk*4+3][row] = bv.w;
    }
    __syncthreads();
#pragma unroll
    for (int k = 0; k < 32; ++k) {
      float4 a0 = *(const float4*)&As[k][ty * 4];
      float4 a1 = *(const float4*)&As[k][64 + ty * 4];
      float4 b0 = *(const float4*)&Bs[k][tx * 4];
      float4 b1 = *(const float4*)&Bs[k][64 + tx * 4];
      float av[8] = {a0.x, a0.y, a0.z, a0.w, a1.x, a1.y, a1.z, a1.w};
      float bv[8] = {b0.x, b0.y, b0.z, b0.w, b1.x, b1.y, b1.z, b1.w};
#pragma unroll
      for (int i = 0; i < 8; ++i)
#pragma unroll
        for (int j = 0; j < 8; ++j) acc[i][j] = fmaf(av[i], bv[j], acc[i][j]);
    }
    __syncthreads();
  }
  // epilogue: store implicit tile + accumulate c2
#pragma unroll
  for (int i = 0; i < 8; ++i) {
    int rl = ((i >> 2) << 6) + ty * 4 + (i & 3);
    int rg = tm0 + rl;
    float s = 0.f;
#pragma unroll
    for (int jh = 0; jh < 2; ++jh) {
      float4 v = make_float4(acc[i][jh*4+0], acc[i][jh*4+1], acc[i][jh*4+2], acc[i][jh*4+3]);
      int cg = tn0 + (jh << 6) + tx * 4;
      *(float4*)(imp + (size_t)rg * DIM + cg) = v;
      s += v.x*v.x + v.y*v.y + v.z*v.z + v.w*v.w;
    }
    atomicAdd(&c2[rg], s);
  }
}

// ---------------------------------------------------------------------------
// Kernel B: fused xc = x @ implicit^T with per-row argmin of (c2[c] - 2*xc).
// Same GEMM structure; epilogue reduces per-row best (packed u64) through LDS
// then one global atomicMin per row per workgroup.
// ---------------------------------------------------------------------------
__global__ __launch_bounds__(256) void k_argmin(
    const float* __restrict__ x, const float* __restrict__ imp,
    const float* __restrict__ c2, unsigned long long* __restrict__ best) {
  __shared__ float As[32][LDSS];
  __shared__ float Bs[32][LDSS];
  const int t  = threadIdx.x;
  const int tx = t & 15, ty = t >> 4;
  const int tm0 = blockIdx.x * 128;   // x rows
  const int tn0 = blockIdx.y * 128;   // codebook entries
  float acc[8][8];
#pragma unroll
  for (int i = 0; i < 8; ++i)
#pragma unroll
    for (int j = 0; j < 8; ++j) acc[i][j] = 0.f;

  const int chunk = t & 7, row0 = t >> 3;
  for (int kt = 0; kt < DIM; kt += 32) {
#pragma unroll
    for (int rr = 0; rr < 4; ++rr) {
      int row = row0 + rr * 32;
      float4 av = *(const float4*)(x   + (size_t)(tm0 + row) * DIM + kt + chunk * 4);
      float4 bv = *(const float4*)(imp + (size_t)(tn0 + row) * DIM + kt + chunk * 4);
      As[chunk*4+0][row] = av.x; As[chunk*4+1][row] = av.y;
      As[chunk*4+2][row] = av.z; As[chunk*4+3][row] = av.w;
      Bs[chunk*4+0][row] = bv.x; Bs[chunk*4+1][row] = bv.y;
      Bs[chunk*4+2][row] = bv.z; Bs[chunk*4+3][row] = bv.w;
    }
    __syncthreads();
#pragma unroll
    for (int k = 0; k < 32; ++k) {
      float4 a0 = *(const float4*)&As[k][ty * 4];
      float4 a1 = *(const float4*)&As[k][64 + ty * 4];
      float4 b0 = *(const float4*)&Bs[k][tx * 4];
      float4 b1 = *(const float4*)&Bs[k][64 + tx * 4];
      float av[8] = {a0.x, a0.y, a0.z, a0.w, a1.x, a1.y, a1.z, a1.w};
      float bv[8] = {b0.x, b0.y, b0.z, b0.w, b1.x, b1.y, b1.z, b1.w};
#pragma unroll
      for (int i = 0; i < 8; ++i)
#pragma unroll
        for (int j = 0; j < 8; ++j) acc[i][j] = fmaf(av[i], bv[j], acc[i][j]);
    }
    __syncthreads();
  }

  // epilogue: per-row argmin of (c2 - 2*xc); pack (key<<32)|col, min-reduce.
  // Hoist the 8 per-column c2 values out of the row loop (load once, not 8x).
  float c2v[8];
  int   cgv[8];
#pragma unroll
  for (int j = 0; j < 8; ++j) {
    cgv[j] = tn0 + ((j >> 2) << 6) + tx * 4 + (j & 3);
    c2v[j] = c2[cgv[j]];
  }
  unsigned long long* red = (unsigned long long*)&As[0][0];  // 16 KB, reuse
#pragma unroll
  for (int i = 0; i < 8; ++i) {
    int rl = ((i >> 2) << 6) + ty * 4 + (i & 3);
    unsigned long long m = ~0ull;
#pragma unroll
    for (int j = 0; j < 8; ++j) {
      float v = c2v[j] - 2.0f * acc[i][j];
      unsigned long long p = ((unsigned long long)fkey(v) << 32) | (unsigned int)cgv[j];
      if (p < m) m = p;
    }
    red[rl * 16 + tx] = m;
  }
  __syncthreads();
  if (t < 128) {
    unsigned long long m = red[t * 16];
#pragma unroll
    for (int s2 = 1; s2 < 16; ++s2) {
      unsigned long long q = red[t * 16 + s2];
      if (q < m) m = q;
    }
    atomicMin(&best[tm0 + t], m);
  }
}

// ---------------------------------------------------------------------------
// Kernel C: gather quantized rows, STE output x + (q - x), indices as float,
// commit loss = mean over rows of sum_d (x-q)^2.  One wave per row.
// ---------------------------------------------------------------------------
__global__ __launch_bounds__(256) void k_gather(
    const float* __restrict__ x, const float* __restrict__ imp,
    const unsigned long long* __restrict__ best,
    float* __restrict__ out_q, float* __restrict__ out_idx,
    float* __restrict__ out_loss) {
  const int wave = threadIdx.x >> 6;
  const int lane = threadIdx.x & 63;
  const int r = blockIdx.x * 4 + wave;
  const unsigned long long p = best[r];
  const int idx = (int)(p & 0xffffffffu);
  const float4* xr = (const float4*)(x   + (size_t)r   * DIM);
  const float4* qr = (const float4*)(imp + (size_t)idx * DIM);
  float4*       o  = (float4*)(out_q + (size_t)r * DIM);
  float s = 0.f;
#pragma unroll
  for (int jh = 0; jh < 2; ++jh) {
    float4 xv = xr[lane + jh * 64];
    float4 qv = qr[lane + jh * 64];
    float4 ov;
    ov.x = xv.x + (qv.x - xv.x);  ov.y = xv.y + (qv.y - xv.y);
    ov.z = xv.z + (qv.z - xv.z);  ov.w = xv.w + (qv.w - xv.w);
    o[lane + jh * 64] = ov;
    float dx = xv.x - qv.x, dy = xv.y - qv.y, dz = xv.z - qv.z, dw = xv.w - qv.w;
    s += dx*dx + dy*dy + dz*dz + dw*dw;
  }
#pragma unroll
  for (int off = 32; off > 0; off >>= 1) s += __shfl_down(s, off);
  if (lane == 0) {
    atomicAdd(out_loss, s * (1.0f / (float)BN));
    out_idx[r] = (float)idx;
  }
}

// ---------------------------------------------------------------------------
extern "C" void kernel_launch(void* const* d_in, const int* in_sizes, int n_in,
                              void* d_out, int out_size, void* d_ws, size_t ws_size,
                              hipStream_t stream) {
  const float* x  = (const float*)d_in[0];  // [4,2048,512]
  const float* Wm = (const float*)d_in[1];  // [512,512]
  const float* cb = (const float*)d_in[2];  // [8192,512]

  float* out   = (float*)d_out;
  float* out_q = out;                          // BN*DIM
  float* out_i = out + (size_t)BN * DIM;       // BN
  float* out_l = out + (size_t)BN * DIM + BN;  // 1

  float* imp = (float*)d_ws;                                          // 16 MiB
  float* c2  = (float*)((char*)d_ws + (size_t)CBSZ * DIM * 4);        // 32 KiB
  unsigned long long* best =
      (unsigned long long*)((char*)d_ws + (size_t)CBSZ * DIM * 4 + CBSZ * 4);  // 64 KiB

  hipMemsetAsync(c2, 0, CBSZ * sizeof(float), stream);
  hipMemsetAsync(best, 0xFF, CBSZ * sizeof(unsigned long long), stream);
  hipMemsetAsync(out_l, 0, sizeof(float), stream);

  dim3 gA(CBSZ / 128, DIM / 128);   // 64 x 4
  k_implicit<<<gA, 256, 0, stream>>>(cb, Wm, imp, c2);

  dim3 gB(BN / 128, CBSZ / 128);    // 64 x 64
  k_argmin<<<gB, 256, 0, stream>>>(x, imp, c2, best);

  k_gather<<<BN / 4, 256, 0, stream>>>(x, imp, best, out_q, out_i, out_l);
}

// Round 4
// 587.369 us; speedup vs baseline: 1.8410x; 1.8410x over previous
//
#include <hip/hip_runtime.h>
#include <stdint.h>

#define DIM   512
#define CBSZ  8192
#define BN    8192
#define LDSS  132       // f32 GEMM pad (k_implicit, unchanged structure)

#define LOSC  4096.0f   // residual scale 2^12 (keeps f16 residuals normal)
#define LOSCI (1.0f/4096.0f)
#define BK    32        // k-tile (f16 elems) for MFMA GEMM
#define AST   72        // LDS row stride in f16: 32 hi + 32 lo + 8 pad = 144 B

typedef _Float16 f16x8 __attribute__((ext_vector_type(8)));
typedef _Float16 f16x4 __attribute__((ext_vector_type(4)));
typedef float    f32x4 __attribute__((ext_vector_type(4)));

// Monotone float->uint mapping: float order == unsigned order.
__device__ __forceinline__ unsigned int fkey(float v) {
  unsigned int u = __float_as_uint(v);
  return (u & 0x80000000u) ? ~u : (u | 0x80000000u);
}

// ---------------------------------------------------------------------------
// Split x (f32) into hi/lo f16 arrays.  lo is scaled by 2^12 so it stays in
// the f16 normal range; the cross-pass accumulator is descaled in the epilogue.
// ---------------------------------------------------------------------------
__global__ __launch_bounds__(256) void k_split(
    const float* __restrict__ in, _Float16* __restrict__ hi,
    _Float16* __restrict__ lo) {
  const int t = blockIdx.x * 256 + threadIdx.x;   // one thread per 8 elems
  const float4* p = (const float4*)in + (size_t)t * 2;
  float4 v0 = p[0], v1 = p[1];
  float vv[8] = {v0.x, v0.y, v0.z, v0.w, v1.x, v1.y, v1.z, v1.w};
  f16x8 h, l;
#pragma unroll
  for (int j = 0; j < 8; ++j) {
    h[j] = (_Float16)vv[j];
    l[j] = (_Float16)((vv[j] - (float)h[j]) * LOSC);
  }
  *(f16x8*)(hi + (size_t)t * 8) = h;
  *(f16x8*)(lo + (size_t)t * 8) = l;
}

// ---------------------------------------------------------------------------
// Kernel A: implicit = codebook @ W^T (f32 vector GEMM, validated round 3),
// epilogue additionally writes hi/lo f16 split of implicit + accumulates c2.
// ---------------------------------------------------------------------------
__global__ __launch_bounds__(256) void k_implicit(
    const float* __restrict__ cb, const float* __restrict__ Wm,
    float* __restrict__ imp, _Float16* __restrict__ imph,
    _Float16* __restrict__ impl, float* __restrict__ c2) {
  __shared__ float As[32][LDSS];
  __shared__ float Bs[32][LDSS];
  const int t  = threadIdx.x;
  const int tx = t & 15, ty = t >> 4;
  const int tm0 = blockIdx.x * 128;
  const int tn0 = blockIdx.y * 128;
  float acc[8][8];
#pragma unroll
  for (int i = 0; i < 8; ++i)
#pragma unroll
    for (int j = 0; j < 8; ++j) acc[i][j] = 0.f;

  const int chunk = t & 7, row0 = t >> 3;
  for (int kt = 0; kt < DIM; kt += 32) {
#pragma unroll
    for (int rr = 0; rr < 4; ++rr) {
      int row = row0 + rr * 32;
      float4 av = *(const float4*)(cb + (size_t)(tm0 + row) * DIM + kt + chunk * 4);
      float4 bv = *(const float4*)(Wm + (size_t)(tn0 + row) * DIM + kt + chunk * 4);
      As[chunk*4+0][row] = av.x; As[chunk*4+1][row] = av.y;
      As[chunk*4+2][row] = av.z; As[chunk*4+3][row] = av.w;
      Bs[chunk*4+0][row] = bv.x; Bs[chunk*4+1][row] = bv.y;
      Bs[chunk*4+2][row] = bv.z; Bs[chunk*4+3][row] = bv.w;
    }
    __syncthreads();
#pragma unroll
    for (int k = 0; k < 32; ++k) {
      float4 a0 = *(const float4*)&As[k][ty * 4];
      float4 a1 = *(const float4*)&As[k][64 + ty * 4];
      float4 b0 = *(const float4*)&Bs[k][tx * 4];
      float4 b1 = *(const float4*)&Bs[k][64 + tx * 4];
      float av[8] = {a0.x, a0.y, a0.z, a0.w, a1.x, a1.y, a1.z, a1.w};
      float bv[8] = {b0.x, b0.y, b0.z, b0.w, b1.x, b1.y, b1.z, b1.w};
#pragma unroll
      for (int i = 0; i < 8; ++i)
#pragma unroll
        for (int j = 0; j < 8; ++j) acc[i][j] = fmaf(av[i], bv[j], acc[i][j]);
    }
    __syncthreads();
  }
#pragma unroll
  for (int i = 0; i < 8; ++i) {
    int rl = ((i >> 2) << 6) + ty * 4 + (i & 3);
    int rg = tm0 + rl;
    float s = 0.f;
#pragma unroll
    for (int jh = 0; jh < 2; ++jh) {
      float4 v = make_float4(acc[i][jh*4+0], acc[i][jh*4+1], acc[i][jh*4+2], acc[i][jh*4+3]);
      int cg = tn0 + (jh << 6) + tx * 4;
      *(float4*)(imp + (size_t)rg * DIM + cg) = v;
      float vs[4] = {v.x, v.y, v.z, v.w};
      f16x4 vh, vl;
#pragma unroll
      for (int q = 0; q < 4; ++q) {
        vh[q] = (_Float16)vs[q];
        vl[q] = (_Float16)((vs[q] - (float)vh[q]) * LOSC);
      }
      *(f16x4*)(imph + (size_t)rg * DIM + cg) = vh;
      *(f16x4*)(impl + (size_t)rg * DIM + cg) = vl;
      s += v.x*v.x + v.y*v.y + v.z*v.z + v.w*v.w;
    }
    atomicAdd(&c2[rg], s);
  }
}

// ---------------------------------------------------------------------------
// Kernel B: fused x @ implicit^T + per-row argmin, f16-split 3-pass MFMA.
// 128x128 tile, BK=32, 4 waves (2x2), 64x64 per wave, 16x16x32_f16 MFMA.
// acc_hh accumulates ah*bh; acc_x accumulates ah*bl + al*bh (scaled 2^12).
// dist-proxy = c2[c] - 2*(hh + x/4096); key-packed u64 argmin via atomicMin.
// ---------------------------------------------------------------------------
__global__ __launch_bounds__(256, 2) void k_argmin(
    const _Float16* __restrict__ xh, const _Float16* __restrict__ xl,
    const _Float16* __restrict__ ch, const _Float16* __restrict__ cl,
    const float* __restrict__ c2, unsigned long long* __restrict__ best) {
  __shared__ _Float16 As[128 * AST];
  __shared__ _Float16 Bs[128 * AST];
  const int t    = threadIdx.x;
  const int lane = t & 63, w = t >> 6;
  const int wm = w >> 1, wn = w & 1;
  const int fr = lane & 15, fq = lane >> 4;
  const int tm0 = blockIdx.x * 128;   // x rows
  const int tn0 = blockIdx.y * 128;   // codebook entries

  f32x4 ahh[4][4], axx[4][4];
#pragma unroll
  for (int i = 0; i < 4; ++i)
#pragma unroll
    for (int j = 0; j < 4; ++j) {
      ahh[i][j] = (f32x4){0.f, 0.f, 0.f, 0.f};
      axx[i][j] = (f32x4){0.f, 0.f, 0.f, 0.f};
    }

  // staging: thread -> (row, hi/lo half); 64 B (= 4 x int4) per side per step
  const int sr = t >> 1, sh = t & 1;
  const _Float16* gA = (sh ? xl : xh) + (size_t)(tm0 + sr) * DIM;
  const _Float16* gB = (sh ? cl : ch) + (size_t)(tn0 + sr) * DIM;
  _Float16* wA = As + sr * AST + sh * 32;
  _Float16* wB = Bs + sr * AST + sh * 32;

  // fragment read bases: lane fr = row-in-16, fq = k-chunk (8 f16 = 16 B)
  const _Float16* rA = As + (wm * 64 + fr) * AST + fq * 8;
  const _Float16* rB = Bs + (wn * 64 + fr) * AST + fq * 8;

  for (int kt = 0; kt < DIM; kt += BK) {
    int4 la0 = *(const int4*)(gA + kt);
    int4 la1 = *(const int4*)(gA + kt + 8);
    int4 la2 = *(const int4*)(gA + kt + 16);
    int4 la3 = *(const int4*)(gA + kt + 24);
    int4 lb0 = *(const int4*)(gB + kt);
    int4 lb1 = *(const int4*)(gB + kt + 8);
    int4 lb2 = *(const int4*)(gB + kt + 16);
    int4 lb3 = *(const int4*)(gB + kt + 24);
    __syncthreads();   // previous compute done reading LDS
    *(int4*)(wA +  0) = la0; *(int4*)(wA +  8) = la1;
    *(int4*)(wA + 16) = la2; *(int4*)(wA + 24) = la3;
    *(int4*)(wB +  0) = lb0; *(int4*)(wB +  8) = lb1;
    *(int4*)(wB + 16) = lb2; *(int4*)(wB + 24) = lb3;
    __syncthreads();   // tile ready

    f16x8 bh[4], bl[4];
#pragma unroll
    for (int j = 0; j < 4; ++j) {
      bh[j] = *(const f16x8*)(rB + j * 16 * AST);
      bl[j] = *(const f16x8*)(rB + j * 16 * AST + 32);
    }
#pragma unroll
    for (int i = 0; i < 4; ++i) {
      f16x8 ah = *(const f16x8*)(rA + i * 16 * AST);
      f16x8 al = *(const f16x8*)(rA + i * 16 * AST + 32);
#pragma unroll
      for (int j = 0; j < 4; ++j) {
        ahh[i][j] = __builtin_amdgcn_mfma_f32_16x16x32_f16(ah, bh[j], ahh[i][j], 0, 0, 0);
        axx[i][j] = __builtin_amdgcn_mfma_f32_16x16x32_f16(ah, bl[j], axx[i][j], 0, 0, 0);
        axx[i][j] = __builtin_amdgcn_mfma_f32_16x16x32_f16(al, bh[j], axx[i][j], 0, 0, 0);
      }
    }
  }

  // epilogue: D row = (lane>>4)*4 + reg, col = lane&15 (m89-verified mapping)
  float c2v[4];
  int   cgv[4];
#pragma unroll
  for (int j = 0; j < 4; ++j) {
    cgv[j] = tn0 + wn * 64 + j * 16 + fr;
    c2v[j] = c2[cgv[j]];
  }
  unsigned long long rmin[4][4];
#pragma unroll
  for (int i = 0; i < 4; ++i)
#pragma unroll
    for (int q = 0; q < 4; ++q) {
      unsigned long long m = ~0ull;
#pragma unroll
      for (int j = 0; j < 4; ++j) {
        float v = c2v[j] - 2.0f * (ahh[i][j][q] + axx[i][j][q] * LOSCI);
        unsigned long long p =
            ((unsigned long long)fkey(v) << 32) | (unsigned int)cgv[j];
        if (p < m) m = p;
      }
      // butterfly min over the 16 lanes sharing this row set
#pragma unroll
      for (int d = 1; d < 16; d <<= 1) {
        unsigned long long o = __shfl_xor(m, d, 64);
        if (o < m) m = o;
      }
      rmin[i][q] = m;
    }
  __syncthreads();
  unsigned long long* red = (unsigned long long*)As;   // 2 x 128 u64 = 2 KB
  if (fr == 0) {
#pragma unroll
    for (int i = 0; i < 4; ++i)
#pragma unroll
      for (int q = 0; q < 4; ++q)
        red[wn * 128 + wm * 64 + i * 16 + fq * 4 + q] = rmin[i][q];
  }
  __syncthreads();
  if (t < 128) {
    unsigned long long a = red[t], b = red[128 + t];
    if (b < a) a = b;
    atomicMin(&best[tm0 + t], a);
  }
}

// ---------------------------------------------------------------------------
// Kernel C: gather + STE + indices + commit loss (unchanged, f32-exact).
// ---------------------------------------------------------------------------
__global__ __launch_bounds__(256) void k_gather(
    const float* __restrict__ x, const float* __restrict__ imp,
    const unsigned long long* __restrict__ best,
    float* __restrict__ out_q, float* __restrict__ out_idx,
    float* __restrict__ out_loss) {
  const int wave = threadIdx.x >> 6;
  const int lane = threadIdx.x & 63;
  const int r = blockIdx.x * 4 + wave;
  const unsigned long long p = best[r];
  const int idx = (int)(p & 0xffffffffu);
  const float4* xr = (const float4*)(x   + (size_t)r   * DIM);
  const float4* qr = (const float4*)(imp + (size_t)idx * DIM);
  float4*       o  = (float4*)(out_q + (size_t)r * DIM);
  float s = 0.f;
#pragma unroll
  for (int jh = 0; jh < 2; ++jh) {
    float4 xv = xr[lane + jh * 64];
    float4 qv = qr[lane + jh * 64];
    float4 ov;
    ov.x = xv.x + (qv.x - xv.x);  ov.y = xv.y + (qv.y - xv.y);
    ov.z = xv.z + (qv.z - xv.z);  ov.w = xv.w + (qv.w - xv.w);
    o[lane + jh * 64] = ov;
    float dx = xv.x - qv.x, dy = xv.y - qv.y, dz = xv.z - qv.z, dw = xv.w - qv.w;
    s += dx*dx + dy*dy + dz*dz + dw*dw;
  }
#pragma unroll
  for (int off = 32; off > 0; off >>= 1) s += __shfl_down(s, off);
  if (lane == 0) {
    atomicAdd(out_loss, s * (1.0f / (float)BN));
    out_idx[r] = (float)idx;
  }
}

// ---------------------------------------------------------------------------
extern "C" void kernel_launch(void* const* d_in, const int* in_sizes, int n_in,
                              void* d_out, int out_size, void* d_ws, size_t ws_size,
                              hipStream_t stream) {
  const float* x  = (const float*)d_in[0];  // [4,2048,512]
  const float* Wm = (const float*)d_in[1];  // [512,512]
  const float* cb = (const float*)d_in[2];  // [8192,512]

  float* out   = (float*)d_out;
  float* out_q = out;
  float* out_i = out + (size_t)BN * DIM;
  float* out_l = out + (size_t)BN * DIM + BN;

  char* ws = (char*)d_ws;
  float* imp = (float*)ws;                                   // 16 MiB
  float* c2  = (float*)(ws + 16777216);                      // 32 KiB
  unsigned long long* best = (unsigned long long*)(ws + 16777216 + 32768);  // 64 KiB
  _Float16* xh = (_Float16*)(ws + 16875520);                 // 8 MiB each
  _Float16* xl = (_Float16*)(ws + 16875520 + 8388608);
  _Float16* ih = (_Float16*)(ws + 16875520 + 2 * 8388608);
  _Float16* il = (_Float16*)(ws + 16875520 + 3 * 8388608);

  hipMemsetAsync(c2, 0, CBSZ * sizeof(float), stream);
  hipMemsetAsync(best, 0xFF, CBSZ * sizeof(unsigned long long), stream);
  hipMemsetAsync(out_l, 0, sizeof(float), stream);

  k_split<<<(BN * DIM / 8) / 256, 256, 0, stream>>>(x, xh, xl);

  dim3 gA(CBSZ / 128, DIM / 128);   // 64 x 4
  k_implicit<<<gA, 256, 0, stream>>>(cb, Wm, imp, ih, il, c2);

  dim3 gB(BN / 128, CBSZ / 128);    // 64 x 64
  k_argmin<<<gB, 256, 0, stream>>>(xh, xl, ih, il, c2, best);

  k_gather<<<BN / 4, 256, 0, stream>>>(x, imp, best, out_q, out_i, out_l);
}